// Round 6
// baseline (2636.850 us; speedup 1.0000x reference)
//
#include <hip/hip_runtime.h>

#define HH 1024
#define WW 1024
#define NB 32
#define PLANE (HH*WW)
typedef unsigned int u32;

// packed half2 ops (HW-verified r4/r5: v_pk_min/max_f16 ignore NaN -> NaN is
// simultaneously the +inf pad for erode and -inf pad for dilate)
static __device__ __forceinline__ u32 pmin(u32 a, u32 b){ u32 d; asm("v_pk_min_f16 %0,%1,%2":"=v"(d):"v"(a),"v"(b)); return d; }
static __device__ __forceinline__ u32 pmax(u32 a, u32 b){ u32 d; asm("v_pk_max_f16 %0,%1,%2":"=v"(d):"v"(a),"v"(b)); return d; }
static __device__ __forceinline__ u32 padd(u32 a, u32 b){ u32 d; asm("v_pk_add_f16 %0,%1,%2":"=v"(d):"v"(a),"v"(b)); return d; }
static __device__ __forceinline__ u32 pmul(u32 a, u32 b){ u32 d; asm("v_pk_mul_f16 %0,%1,%2":"=v"(d):"v"(a),"v"(b)); return d; }
static __device__ __forceinline__ u32 psub(u32 a, u32 b){ u32 d; asm("v_pk_add_f16 %0,%1,%2 neg_lo:[0,1] neg_hi:[0,1]":"=v"(d):"v"(a),"v"(b)); return d; }
static __device__ __forceinline__ float h2f(u32 s){ float f; asm("v_cvt_f32_f16 %0,%1":"=v"(f):"v"(s)); return f; }
static __device__ __forceinline__ u32 cvt2(float a, float b){
    typedef __fp16 h2v __attribute__((ext_vector_type(2)));
    union { h2v h; u32 u; } r; r.h = __builtin_amdgcn_cvt_pkrtz(a,b); return r.u;
}
// DPP lane+-1 within 16-lane rows == the 16 col-groups of one strip (lane = s*16+c)
#define DPP_SHR1(x) ((u32)__builtin_amdgcn_mov_dpp((int)(x), 0x111, 0xf, 0xf, true))
#define DPP_SHL1(x) ((u32)__builtin_amdgcn_mov_dpp((int)(x), 0x101, 0xf, 0xf, true))
#define QNAN2 0x7e007e00u
#define AB(hi,lo) (((lo)>>16)|((hi)<<16))
#define QN4 make_uint4(QNAN2,QNAN2,QNAN2,QNAN2)

// 5-point cross erode of one 8-px row triple (all register inputs)
static __device__ __forceinline__ uint4 erode_row(uint4 up, uint4 md, uint4 dn){
    u32 lfs = DPP_SHR1(md.w);
    u32 rts = DPP_SHL1(md.x);
    u32 vx = pmin(up.x,dn.x), vy = pmin(up.y,dn.y);
    u32 vz = pmin(up.z,dn.z), vw = pmin(up.w,dn.w);
    u32 B1 = AB(md.y,md.x), B2 = AB(md.z,md.y), B3 = AB(md.w,md.z);
    u32 B4 = (md.w>>16)|(rts<<16);
    u32 M0 = (md.x<<16)|(lfs>>16);
    uint4 e;
    e.x = pmin(pmin(vx,md.x), pmin(M0,B1));
    e.y = pmin(pmin(vy,md.y), pmin(B1,B2));
    e.z = pmin(pmin(vz,md.z), pmin(B2,B3));
    e.w = pmin(pmin(vw,md.w), pmin(B3,B4));
    return e;
}

// Tile 64w x 128h. Region rows [by-27, by+154] (0..181), cols [bx-32, bx+95]
// (16 groups of 8px). 384 threads = 24 strips x 16 col-groups; strip s owns
// rows 8s..8s+7 in registers; x[k] = row 8s-1+k.
__global__ __launch_bounds__(384,3) void cldice_fused(const float* __restrict__ inputs,
                                                      const float* __restrict__ target,
                                                      double* __restrict__ acc) {
    __shared__ uint4 ex[2][24][2][16];   // ping-pong boundary-row exchange (24.6 KB)
    const int tid = threadIdx.x;
    const int s = tid >> 4, c = tid & 15;
    const int bx = blockIdx.x*64, by = blockIdx.y*128;
    const int img = blockIdx.z >> 5, n = blockIdx.z & 31;
    const float* xsrc = (img==0) ? inputs : target;   // skeletonize this
    const float* wsrc = (img==0) ? target : inputs;   // weight for tprec/tsens
    const float* im = xsrc + (size_t)n*PLANE;
    const int gx = bx - 32 + 8*c;
    const bool colok = ((unsigned)gx < (unsigned)WW);
    const int rbase = 8*s;
    const bool skelcol = (c >= 4 && c <= 11);   // tile cols = groups 4..11

    uint4 x[10], e[8], sk[8];
    bool nok[8];
    #pragma unroll
    for (int k = 0; k < 10; k++) {
        int r = rbase - 1 + k, gy = by - 27 + r;
        if (colok && r >= 0 && r <= 181 && gy >= 0 && gy < HH) {
            const float* p = im + (size_t)gy*WW + gx;
            float4 f0 = *(const float4*)p, f1 = *(const float4*)(p+4);
            x[k].x = cvt2(f0.x,f0.y); x[k].y = cvt2(f0.z,f0.w);
            x[k].z = cvt2(f1.x,f1.y); x[k].w = cvt2(f1.z,f1.w);
        } else x[k] = QN4;
    }
    #pragma unroll
    for (int i = 0; i < 8; i++) {
        int r = rbase + i, gy = by - 27 + r;
        nok[i] = !(colok && r <= 181 && gy >= 0 && gy < HH);
        e[i] = QN4;
        sk[i] = make_uint4(0,0,0,0);
    }

    #pragma unroll 1
    for (int t = 0; t < 26; t++) {
        // ---- erode x_t rows rbase..rbase+7 (active window only) ----
        #pragma unroll
        for (int i = 0; i < 8; i++) {
            int r = rbase + i;                 // uniform per 16-lane DPP row
            if (r >= t+1 && r <= 180-t) {
                uint4 ev = erode_row(x[i], x[i+1], x[i+2]);
                if (nok[i]) ev = QN4;          // out-of-image rows stay NaN pad
                e[i] = ev;
            }
        }
        // ---- boundary exchange (ping-pong; 1 barrier/step) ----
        uint4 (*exb)[2][16] = ex[t&1];
        exb[s][0][c] = e[0];
        exb[s][1][c] = e[7];
        __syncthreads();
        uint4 xm1 = (s > 0)  ? exb[s-1][1][c] : QN4;   // x_{t+1} row rbase-1
        uint4 xp8 = (s < 23) ? exb[s+1][0][c] : QN4;   // x_{t+1} row rbase+8
        // ---- dilate3x3(x_{t+1}) at tile rows; delta vs x_t; skel update ----
        #pragma unroll
        for (int i = 0; i < 8; i++) {
            int r = rbase + i;                 // uniform per 16-lane DPP row
            if (r >= 27 && r <= 154) {
                uint4 em = (i == 0) ? xm1 : e[i-1];
                uint4 ep = (i == 7) ? xp8 : e[i+1];
                uint4 ec = e[i];
                uint4 vm;
                vm.x = pmax(pmax(em.x,ep.x),ec.x);
                vm.y = pmax(pmax(em.y,ep.y),ec.y);
                vm.z = pmax(pmax(em.z,ep.z),ec.z);
                vm.w = pmax(pmax(em.w,ep.w),ec.w);
                u32 lfm = DPP_SHR1(vm.w);      // all 16 lanes: c=4..11 read c=3..12
                u32 rtm = DPP_SHL1(vm.x);
                if (skelcol) {
                    u32 B1 = AB(vm.y,vm.x), B2 = AB(vm.z,vm.y), B3 = AB(vm.w,vm.z);
                    u32 B4 = (vm.w>>16)|(rtm<<16);
                    u32 M0 = (vm.x<<16)|(lfm>>16);
                    uint4 d;
                    d.x = pmax(pmax(M0,B1), vm.x);
                    d.y = pmax(pmax(B1,B2), vm.y);
                    d.z = pmax(pmax(B2,B3), vm.z);
                    d.w = pmax(pmax(B3,B4), vm.w);
                    uint4 xs = x[i+1];         // x_t (pre-update)
                    uint4 dl;
                    dl.x = pmax(psub(xs.x,d.x), 0u);
                    dl.y = pmax(psub(xs.y,d.y), 0u);
                    dl.z = pmax(psub(xs.z,d.z), 0u);
                    dl.w = pmax(psub(xs.w,d.w), 0u);
                    sk[i].x = padd(sk[i].x, pmax(psub(dl.x, pmul(sk[i].x,dl.x)), 0u));
                    sk[i].y = padd(sk[i].y, pmax(psub(dl.y, pmul(sk[i].y,dl.y)), 0u));
                    sk[i].z = padd(sk[i].z, pmax(psub(dl.z, pmul(sk[i].z,dl.z)), 0u));
                    sk[i].w = padd(sk[i].w, pmax(psub(dl.w, pmul(sk[i].w,dl.w)), 0u));
                }
            }
        }
        // ---- x <- x_{t+1} (inactive rows keep stale values: never read) ----
        x[0] = xm1;
        #pragma unroll
        for (int i = 0; i < 8; i++) {
            int r = rbase + i;
            if (r >= t+1 && r <= 180-t) x[i+1] = e[i];
        }
        x[9] = xp8;
    }

    // ---- fused reduction: s0 = sum(skel*w), s1 = sum(skel) ----
    double s0 = 0.0, s1 = 0.0;
    if (skelcol) {
        const float* wim = wsrc + (size_t)n*PLANE;
        #pragma unroll
        for (int i = 0; i < 8; i++) {
            int r = rbase + i;
            if (r >= 27 && r <= 154) {
                int gy = by - 27 + r;
                const float* p = wim + (size_t)gy*WW + gx;
                float4 w0 = *(const float4*)p, w1 = *(const float4*)(p+4);
                float f0 = h2f(sk[i].x&0xffffu), f1 = h2f(sk[i].x>>16);
                float f2 = h2f(sk[i].y&0xffffu), f3 = h2f(sk[i].y>>16);
                float f4 = h2f(sk[i].z&0xffffu), f5 = h2f(sk[i].z>>16);
                float f6 = h2f(sk[i].w&0xffffu), f7 = h2f(sk[i].w>>16);
                s0 += (double)(f0*w0.x) + (double)(f1*w0.y) + (double)(f2*w0.z) + (double)(f3*w0.w)
                    + (double)(f4*w1.x) + (double)(f5*w1.y) + (double)(f6*w1.z) + (double)(f7*w1.w);
                s1 += (double)f0 + (double)f1 + (double)f2 + (double)f3
                    + (double)f4 + (double)f5 + (double)f6 + (double)f7;
            }
        }
    }
    #pragma unroll
    for (int off = 32; off > 0; off >>= 1) {
        s0 += __shfl_down(s0, off, 64);
        s1 += __shfl_down(s1, off, 64);
    }
    __syncthreads();               // ex dead; reuse for block reduction
    double* sh = (double*)ex;
    int lane = tid & 63, wid = tid >> 6;   // 6 waves
    if (lane == 0) { sh[wid] = s0; sh[6+wid] = s1; }
    __syncthreads();
    if (tid == 0) {
        atomicAdd(&acc[img*2 + 0], sh[0]+sh[1]+sh[2]+sh[3]+sh[4]+sh[5]);
        atomicAdd(&acc[img*2 + 1], sh[6]+sh[7]+sh[8]+sh[9]+sh[10]+sh[11]);
    }
}

__global__ void final_kernel(const double* __restrict__ acc, float* __restrict__ out) {
    double tprec = (acc[0] + 1e-5) / (acc[1] + 1e-5);
    double tsens = (acc[2] + 1e-5) / (acc[3] + 1e-5);
    out[0] = (float)(1.0 - 2.0 * (tprec * tsens) / (tprec + tsens));
}

extern "C" void kernel_launch(void* const* d_in, const int* in_sizes, int n_in,
                              void* d_out, int out_size, void* d_ws, size_t ws_size,
                              hipStream_t stream) {
    const float* target = (const float*)d_in[0];
    const float* inputs = (const float*)d_in[1];
    float* out = (float*)d_out;
    double* acc = (double*)d_ws;

    (void)hipMemsetAsync(acc, 0, 4*sizeof(double), stream);
    dim3 grid(WW/64, HH/128, NB*2);
    cldice_fused<<<grid, dim3(384), 0, stream>>>(inputs, target, acc);
    final_kernel<<<1, 1, 0, stream>>>(acc, out);
}